// Round 1
// baseline (7783.295 us; speedup 1.0000x reference)
//
#include <hip/hip_runtime.h>
#include <math.h>

// Problem constants
constexpr int Bn  = 2;
constexpr int CIN = 4;
constexpr int N1c = 32, N2c = 64, N3c = 96, N4c = 128;
constexpr int MQn = 1024;
constexpr int D0 = 64, D1 = 32, D2 = 16, D3 = 8;

// Output layout (floats): x [2,128,8,8,8] = 131072, q [1,2,2] = 4, k [3,2] = 6
constexpr int OUT_X = 0;
constexpr int OUT_Q = 131072;
constexpr int OUT_K = 131076;

// Workspace layout (floats)
constexpr size_t OFF_CNT   = 0;                 // c0[2], c1[2], c2[2]
constexpr size_t OFF_SCALE = 6;                 // scale[2]
constexpr size_t OFF_M1    = 8;                 // 2*32^3 = 65536
constexpr size_t OFF_M2    = OFF_M1 + 65536;    // 2*16^3 = 8192
constexpr size_t OFF_M3    = OFF_M2 + 8192;     // 2*8^3  = 1024
constexpr size_t OFF_T1    = OFF_M3 + 1024;     // 2*32*32^3 = 2097152
constexpr size_t OFF_Y1    = OFF_T1 + 2097152;
constexpr size_t OFF_T2    = OFF_Y1 + 2097152;  // 2*64*16^3 = 524288
constexpr size_t OFF_Y2    = OFF_T2 + 524288;
constexpr size_t OFF_T3    = OFF_Y2 + 524288;   // 2*96*8^3 = 98304
constexpr size_t OFF_Y3    = OFF_T3 + 98304;
// total ~5.5M floats (~22 MB)

__global__ void qmean_kernel(const float* __restrict__ QF, float* __restrict__ out_q,
                             float* __restrict__ scale) {
    int b = blockIdx.x >> 1, c = blockIdx.x & 1;
    float s = 0.f;
    for (int m = threadIdx.x; m < MQn; m += blockDim.x)
        s += QF[(b * MQn + m) * 2 + c];
    __shared__ float sh[256];
    sh[threadIdx.x] = s;
    __syncthreads();
    for (int st = 128; st > 0; st >>= 1) {
        if (threadIdx.x < st) sh[threadIdx.x] += sh[threadIdx.x + st];
        __syncthreads();
    }
    if (threadIdx.x == 0) {
        float mean = sh[0] / (float)MQn;
        out_q[b * 2 + c] = mean;
        if (c == 0) scale[b] = mean;
    }
}

// Derive m0 from x_feat (any channel nonzero), pool to m1, count c0.
__global__ void mask_pool1_kernel(const float* __restrict__ xf, float* __restrict__ m1,
                                  float* __restrict__ c0) {
    int idx = blockIdx.x * blockDim.x + threadIdx.x;   // 0..65535
    int b = idx >> 15;
    int v = idx & 32767;
    int oz = v >> 10, oy = (v >> 5) & 31, ox = v & 31;
    float cnt = 0.f;
    float mx = 0.f;
    for (int dz = 0; dz < 2; ++dz)
        for (int dy = 0; dy < 2; ++dy)
            for (int dx = 0; dx < 2; ++dx) {
                int z = 2 * oz + dz, y = 2 * oy + dy, x = 2 * ox + dx;
                size_t base = (size_t)b * CIN * D0 * D0 * D0 + ((size_t)z * D0 + y) * D0 + x;
                bool occ = false;
                for (int c = 0; c < CIN; ++c)
                    occ = occ || (xf[base + (size_t)c * D0 * D0 * D0] != 0.f);
                if (occ) { cnt += 1.f; mx = 1.f; }
            }
    m1[idx] = mx;
    __shared__ float sh[256];
    sh[threadIdx.x] = cnt;
    __syncthreads();
    for (int st = 128; st > 0; st >>= 1) {
        if (threadIdx.x < st) sh[threadIdx.x] += sh[threadIdx.x + st];
        __syncthreads();
    }
    if (threadIdx.x == 0) atomicAdd(&c0[b], sh[0]);  // b uniform per block (32768 % 256 == 0)
}

// Generic 2x2x2 max-pool on a mask + count of input mask
__global__ void pool_kernel(const float* __restrict__ min_, float* __restrict__ mout,
                            float* __restrict__ cacc, int Din) {
    int Do = Din >> 1;
    int per = Do * Do * Do;
    int idx = blockIdx.x * blockDim.x + threadIdx.x;
    int b = idx / per;
    int v = idx % per;
    int oz = v / (Do * Do), oy = (v / Do) % Do, ox = v % Do;
    float s = 0.f, mx = 0.f;
    for (int dz = 0; dz < 2; ++dz)
        for (int dy = 0; dy < 2; ++dy)
            for (int dx = 0; dx < 2; ++dx) {
                float val = min_[(((size_t)b * Din + 2 * oz + dz) * Din + 2 * oy + dy) * Din + 2 * ox + dx];
                s += val;
                mx = fmaxf(mx, val);
            }
    mout[idx] = mx;
    __shared__ float sh[256];
    sh[threadIdx.x] = s;
    __syncthreads();
    for (int st = 128; st > 0; st >>= 1) {
        if (threadIdx.x < st) sh[threadIdx.x] += sh[threadIdx.x + st];
        __syncthreads();
    }
    if (threadIdx.x == 0) atomicAdd(&cacc[b], sh[0]);
}

__global__ void writek_kernel(const float* __restrict__ cnt, float* __restrict__ outk) {
    int i = threadIdx.x;
    if (i < 6) {
        int row = i >> 1, b = i & 1;  // row0=c2, row1=c1, row2=c0
        float v = (row == 0) ? cnt[4 + b] : (row == 1 ? cnt[2 + b] : cnt[b]);
        outk[i] = v;
    }
}

// Direct conv3d, 5x5x5, pad 2, output masked: out = (conv + bias) * mask
__global__ void conv3d_kernel(const float* __restrict__ in, const float* __restrict__ w,
                              const float* __restrict__ bias, const float* __restrict__ mask,
                              float* __restrict__ out,
                              int Cin, int Cout, int Din, int Dout, int stride) {
    int idx = blockIdx.x * blockDim.x + threadIdx.x;
    int total = Bn * Cout * Dout * Dout * Dout;
    if (idx >= total) return;
    int x = idx % Dout;
    int t = idx / Dout;
    int y = t % Dout; t /= Dout;
    int z = t % Dout; t /= Dout;
    int co = t % Cout;
    int b = t / Cout;
    float mval = mask[(((size_t)b * Dout + z) * Dout + y) * Dout + x];
    if (mval == 0.f) { out[idx] = 0.f; return; }
    float acc = bias[co];
    int z0 = z * stride - 2, y0 = y * stride - 2, x0 = x * stride - 2;
    for (int ci = 0; ci < Cin; ++ci) {
        const float* inp = in + (size_t)(b * Cin + ci) * Din * Din * Din;
        const float* wp = w + (size_t)(co * Cin + ci) * 125;
        for (int kz = 0; kz < 5; ++kz) {
            int iz = z0 + kz;
            if ((unsigned)iz >= (unsigned)Din) continue;
            for (int ky = 0; ky < 5; ++ky) {
                int iy = y0 + ky;
                if ((unsigned)iy >= (unsigned)Din) continue;
                const float* row = inp + ((size_t)iz * Din + iy) * Din;
                const float* wr = wp + (kz * 5 + ky) * 5;
#pragma unroll
                for (int kx = 0; kx < 5; ++kx) {
                    int ix = x0 + kx;
                    if ((unsigned)ix < (unsigned)Din) acc += row[ix] * wr[kx];
                }
            }
        }
    }
    out[idx] = acc * mval;
}

// GDN: y = t * rsqrt(beta + conv5(gamma, t^2)) * scale.  t already masked, so t==0 -> y==0.
__global__ void gdn_kernel(const float* __restrict__ tbuf, const float* __restrict__ gamma,
                           const float* __restrict__ beta, const float* __restrict__ scale,
                           float* __restrict__ y, int C, int Dd) {
    int idx = blockIdx.x * blockDim.x + threadIdx.x;
    int total = Bn * C * Dd * Dd * Dd;
    if (idx >= total) return;
    int x = idx % Dd;
    int t = idx / Dd;
    int yy = t % Dd; t /= Dd;
    int z = t % Dd; t /= Dd;
    int co = t % C;
    int b = t / C;
    float tv = tbuf[idx];
    if (tv == 0.f) { y[idx] = 0.f; return; }
    float den = beta[co];
    int z0 = z - 2, y0 = yy - 2, x0 = x - 2;
    for (int ci = 0; ci < C; ++ci) {
        const float* inp = tbuf + (size_t)(b * C + ci) * Dd * Dd * Dd;
        const float* wp = gamma + (size_t)(co * C + ci) * 125;
        for (int kz = 0; kz < 5; ++kz) {
            int iz = z0 + kz;
            if ((unsigned)iz >= (unsigned)Dd) continue;
            for (int ky = 0; ky < 5; ++ky) {
                int iy = y0 + ky;
                if ((unsigned)iy >= (unsigned)Dd) continue;
                const float* row = inp + ((size_t)iz * Dd + iy) * Dd;
                const float* wr = wp + (kz * 5 + ky) * 5;
#pragma unroll
                for (int kx = 0; kx < 5; ++kx) {
                    int ix = x0 + kx;
                    if ((unsigned)ix < (unsigned)Dd) {
                        float v = row[ix];
                        den += v * v * wr[kx];
                    }
                }
            }
        }
    }
    y[idx] = tv * rsqrtf(den) * scale[b];
}

extern "C" void kernel_launch(void* const* d_in, const int* in_sizes, int n_in,
                              void* d_out, int out_size, void* d_ws, size_t ws_size,
                              hipStream_t stream) {
    const float* x_feat = (const float*)d_in[0];
    const float* QF     = (const float*)d_in[2];
    const float* w1 = (const float*)d_in[3];  const float* b1 = (const float*)d_in[4];
    const float* w2 = (const float*)d_in[5];  const float* b2 = (const float*)d_in[6];
    const float* w3 = (const float*)d_in[7];  const float* b3 = (const float*)d_in[8];
    const float* w4 = (const float*)d_in[9];  const float* b4 = (const float*)d_in[10];
    const float* beta1 = (const float*)d_in[11]; const float* gamma1 = (const float*)d_in[12];
    const float* beta2 = (const float*)d_in[13]; const float* gamma2 = (const float*)d_in[14];
    const float* beta3 = (const float*)d_in[15]; const float* gamma3 = (const float*)d_in[16];

    float* out = (float*)d_out;
    float* ws = (float*)d_ws;
    float* cnt   = ws + OFF_CNT;
    float* scale = ws + OFF_SCALE;
    float* m1 = ws + OFF_M1;
    float* m2 = ws + OFF_M2;
    float* m3 = ws + OFF_M3;
    float* t1 = ws + OFF_T1;
    float* y1 = ws + OFF_Y1;
    float* t2 = ws + OFF_T2;
    float* y2 = ws + OFF_Y2;
    float* t3 = ws + OFF_T3;
    float* y3 = ws + OFF_Y3;

    hipMemsetAsync(cnt, 0, 6 * sizeof(float), stream);

    qmean_kernel<<<4, 256, 0, stream>>>(QF, out + OUT_Q, scale);
    mask_pool1_kernel<<<256, 256, 0, stream>>>(x_feat, m1, cnt + 0);
    pool_kernel<<<32, 256, 0, stream>>>(m1, m2, cnt + 2, D1);
    pool_kernel<<<4, 256, 0, stream>>>(m2, m3, cnt + 4, D2);
    writek_kernel<<<1, 64, 0, stream>>>(cnt, out + OUT_K);

    // Stage 1: conv1 (4->32, 64->32, s2) + GDN1
    conv3d_kernel<<<8192, 256, 0, stream>>>(x_feat, w1, b1, m1, t1, CIN, N1c, D0, D1, 2);
    gdn_kernel<<<8192, 256, 0, stream>>>(t1, gamma1, beta1, scale, y1, N1c, D1);

    // Stage 2: conv2 (32->64, 32->16, s2) + GDN2
    conv3d_kernel<<<2048, 256, 0, stream>>>(y1, w2, b2, m2, t2, N1c, N2c, D1, D2, 2);
    gdn_kernel<<<2048, 256, 0, stream>>>(t2, gamma2, beta2, scale, y2, N2c, D2);

    // Stage 3: conv3 (64->96, 16->8, s2) + GDN3
    conv3d_kernel<<<384, 256, 0, stream>>>(y2, w3, b3, m3, t3, N2c, N3c, D2, D3, 2);
    gdn_kernel<<<384, 256, 0, stream>>>(t3, gamma3, beta3, scale, y3, N3c, D3);

    // Stage 4: conv4 (96->128, 8->8, s1), masked by m3, straight to output
    conv3d_kernel<<<512, 256, 0, stream>>>(y3, w4, b4, m3, out + OUT_X, N3c, N4c, D3, D3, 1);
}

// Round 2
// 3358.114 us; speedup vs baseline: 2.3178x; 2.3178x over previous
//
#include <hip/hip_runtime.h>
#include <math.h>

// Problem constants
constexpr int Bn  = 2;
constexpr int CIN = 4;
constexpr int N1c = 32, N2c = 64, N3c = 96, N4c = 128;
constexpr int MQn = 1024;
constexpr int D0 = 64, D1 = 32, D2 = 16, D3 = 8;

// Output layout (floats): x [2,128,8,8,8] = 131072, q [1,2,2] = 4, k [3,2] = 6
constexpr int OUT_X = 0;
constexpr int OUT_Q = 131072;
constexpr int OUT_K = 131076;

// Workspace layout (floats)
constexpr size_t OFF_CNT   = 0;                 // c0[2], c1[2], c2[2]
constexpr size_t OFF_SCALE = 6;                 // scale[2]
constexpr size_t OFF_M1    = 8;                 // 2*32^3 = 65536
constexpr size_t OFF_M2    = OFF_M1 + 65536;    // 2*16^3 = 8192
constexpr size_t OFF_M3    = OFF_M2 + 8192;     // 2*8^3  = 1024
constexpr size_t OFF_T1    = OFF_M3 + 1024;     // 2*32*32^3 = 2097152
constexpr size_t OFF_Y1    = OFF_T1 + 2097152;
constexpr size_t OFF_T2    = OFF_Y1 + 2097152;  // 2*64*16^3 = 524288
constexpr size_t OFF_Y2    = OFF_T2 + 524288;
constexpr size_t OFF_T3    = OFF_Y2 + 524288;   // 2*96*8^3 = 98304
constexpr size_t OFF_Y3    = OFF_T3 + 98304;

__global__ void qmean_kernel(const float* __restrict__ QF, float* __restrict__ out_q,
                             float* __restrict__ scale) {
    int b = blockIdx.x >> 1, c = blockIdx.x & 1;
    float s = 0.f;
    for (int m = threadIdx.x; m < MQn; m += blockDim.x)
        s += QF[(b * MQn + m) * 2 + c];
    __shared__ float sh[256];
    sh[threadIdx.x] = s;
    __syncthreads();
    for (int st = 128; st > 0; st >>= 1) {
        if (threadIdx.x < st) sh[threadIdx.x] += sh[threadIdx.x + st];
        __syncthreads();
    }
    if (threadIdx.x == 0) {
        float mean = sh[0] / (float)MQn;
        out_q[b * 2 + c] = mean;
        if (c == 0) scale[b] = mean;
    }
}

// Derive m0 from x_feat (any channel nonzero), pool to m1, count c0.
__global__ void mask_pool1_kernel(const float* __restrict__ xf, float* __restrict__ m1,
                                  float* __restrict__ c0) {
    int idx = blockIdx.x * blockDim.x + threadIdx.x;   // 0..65535
    int b = idx >> 15;
    int v = idx & 32767;
    int oz = v >> 10, oy = (v >> 5) & 31, ox = v & 31;
    float cnt = 0.f;
    float mx = 0.f;
    for (int dz = 0; dz < 2; ++dz)
        for (int dy = 0; dy < 2; ++dy)
            for (int dx = 0; dx < 2; ++dx) {
                int z = 2 * oz + dz, y = 2 * oy + dy, x = 2 * ox + dx;
                size_t base = (size_t)b * CIN * D0 * D0 * D0 + ((size_t)z * D0 + y) * D0 + x;
                bool occ = false;
                for (int c = 0; c < CIN; ++c)
                    occ = occ || (xf[base + (size_t)c * D0 * D0 * D0] != 0.f);
                if (occ) { cnt += 1.f; mx = 1.f; }
            }
    m1[idx] = mx;
    __shared__ float sh[256];
    sh[threadIdx.x] = cnt;
    __syncthreads();
    for (int st = 128; st > 0; st >>= 1) {
        if (threadIdx.x < st) sh[threadIdx.x] += sh[threadIdx.x + st];
        __syncthreads();
    }
    if (threadIdx.x == 0) atomicAdd(&c0[b], sh[0]);
}

__global__ void pool_kernel(const float* __restrict__ min_, float* __restrict__ mout,
                            float* __restrict__ cacc, int Din) {
    int Do = Din >> 1;
    int per = Do * Do * Do;
    int idx = blockIdx.x * blockDim.x + threadIdx.x;
    int b = idx / per;
    int v = idx % per;
    int oz = v / (Do * Do), oy = (v / Do) % Do, ox = v % Do;
    float s = 0.f, mx = 0.f;
    for (int dz = 0; dz < 2; ++dz)
        for (int dy = 0; dy < 2; ++dy)
            for (int dx = 0; dx < 2; ++dx) {
                float val = min_[(((size_t)b * Din + 2 * oz + dz) * Din + 2 * oy + dy) * Din + 2 * ox + dx];
                s += val;
                mx = fmaxf(mx, val);
            }
    mout[idx] = mx;
    __shared__ float sh[256];
    sh[threadIdx.x] = s;
    __syncthreads();
    for (int st = 128; st > 0; st >>= 1) {
        if (threadIdx.x < st) sh[threadIdx.x] += sh[threadIdx.x + st];
        __syncthreads();
    }
    if (threadIdx.x == 0) atomicAdd(&cacc[b], sh[0]);
}

__global__ void writek_kernel(const float* __restrict__ cnt, float* __restrict__ outk) {
    int i = threadIdx.x;
    if (i < 6) {
        int row = i >> 1, b = i & 1;  // row0=c2, row1=c1, row2=c0
        float v = (row == 0) ? cnt[4 + b] : (row == 1 ? cnt[2 + b] : cnt[b]);
        outk[i] = v;
    }
}

// Tiled 5x5x5 conv, pad 2. Block = (batch, co-chunk, spatial tile 4x8x8 of output).
// Per ci: stage input tile in LDS (squared for GDN), then 125 taps x CO_TILE reg FMAs.
// Weights fetched with wave-uniform indices -> scalar loads.
// GDN=false: out = (acc + bias)*mask.  GDN=true: out = t * rsqrt(beta + acc) * scale.
template<int CINt, int COUTt, int CO_TILE, int DIN, int DOUT, int STRIDE, bool GDN>
__global__ __launch_bounds__(256) void conv_tile_kernel(
    const float* __restrict__ in, const float* __restrict__ w,
    const float* __restrict__ bb,      // bias (conv) or beta (gdn)
    const float* __restrict__ mask,    // conv only (may be null for gdn)
    const float* __restrict__ scale,   // gdn only (may be null for conv)
    float* __restrict__ out)
{
    constexpr int TZ = 4, TY = 8, TX = 8;
    constexpr int LZ = (STRIDE == 1) ? TZ + 4 : 2 * TZ + 3;
    constexpr int LY = (STRIDE == 1) ? TY + 4 : 2 * TY + 3;
    constexpr int LX = (STRIDE == 1) ? TX + 4 : 2 * TX + 3;
    constexpr int NTZ = DOUT / TZ, NTY = DOUT / TY, NTX = DOUT / TX;
    constexpr int NT = NTZ * NTY * NTX;
    constexpr int NCH = COUTt / CO_TILE;
    constexpr int LN = LZ * LY * LX;
    __shared__ float sh[LN];

    int tile  = blockIdx.x % NT;
    int chunk = (blockIdx.x / NT) % NCH;
    int b     = blockIdx.x / (NT * NCH);
    int tz0 = (tile / (NTY * NTX)) * TZ;
    int ty0 = ((tile / NTX) % NTY) * TY;
    int tx0 = (tile % NTX) * TX;
    int co0 = chunk * CO_TILE;

    int tid = threadIdx.x;
    int tx = tid & (TX - 1);
    int ty = (tid >> 3) & (TY - 1);
    int tz = tid >> 6;

    float acc[CO_TILE];
#pragma unroll
    for (int j = 0; j < CO_TILE; ++j) acc[j] = 0.f;

    int iz0 = tz0 * STRIDE - 2, iy0 = ty0 * STRIDE - 2, ix0 = tx0 * STRIDE - 2;

    for (int ci = 0; ci < CINt; ++ci) {
        const float* inp = in + (size_t)(b * CINt + ci) * DIN * DIN * DIN;
        __syncthreads();   // protect sh[] from previous iteration's readers
        for (int i = tid; i < LN; i += 256) {
            int lx = i % LX, rem = i / LX;
            int ly = rem % LY, lz = rem / LY;
            int gz = iz0 + lz, gy = iy0 + ly, gx = ix0 + lx;
            float v = 0.f;
            if ((unsigned)gz < (unsigned)DIN && (unsigned)gy < (unsigned)DIN &&
                (unsigned)gx < (unsigned)DIN)
                v = inp[((size_t)gz * DIN + gy) * DIN + gx];
            sh[i] = GDN ? v * v : v;
        }
        __syncthreads();
        const float* wci = w + ((size_t)co0 * CINt + ci) * 125;
        for (int kz = 0; kz < 5; ++kz) {
            for (int ky = 0; ky < 5; ++ky) {
                int base = ((tz * STRIDE + kz) * LY + ty * STRIDE + ky) * LX + tx * STRIDE;
                int t0 = (kz * 5 + ky) * 5;
#pragma unroll
                for (int kx = 0; kx < 5; ++kx) {
                    float v = sh[base + kx];
#pragma unroll
                    for (int j = 0; j < CO_TILE; ++j)
                        acc[j] += v * wci[(size_t)j * CINt * 125 + t0 + kx];
                }
            }
        }
    }

    // epilogue
    int z = tz0 + tz, y = ty0 + ty, x = tx0 + tx;
    size_t sp = ((size_t)z * DOUT + y) * DOUT + x;
    if (GDN) {
        float sc = scale[b];
#pragma unroll
        for (int j = 0; j < CO_TILE; ++j) {
            int co = co0 + j;
            size_t oidx = (size_t)(b * COUTt + co) * DOUT * DOUT * DOUT + sp;
            float tv = in[oidx];
            out[oidx] = tv * rsqrtf(bb[co] + acc[j]) * sc;
        }
    } else {
        float mval = mask[(size_t)b * DOUT * DOUT * DOUT + sp];
#pragma unroll
        for (int j = 0; j < CO_TILE; ++j) {
            int co = co0 + j;
            size_t oidx = (size_t)(b * COUTt + co) * DOUT * DOUT * DOUT + sp;
            out[oidx] = (acc[j] + bb[co]) * mval;
        }
    }
}

extern "C" void kernel_launch(void* const* d_in, const int* in_sizes, int n_in,
                              void* d_out, int out_size, void* d_ws, size_t ws_size,
                              hipStream_t stream) {
    const float* x_feat = (const float*)d_in[0];
    const float* QF     = (const float*)d_in[2];
    const float* w1 = (const float*)d_in[3];  const float* b1 = (const float*)d_in[4];
    const float* w2 = (const float*)d_in[5];  const float* b2 = (const float*)d_in[6];
    const float* w3 = (const float*)d_in[7];  const float* b3 = (const float*)d_in[8];
    const float* w4 = (const float*)d_in[9];  const float* b4 = (const float*)d_in[10];
    const float* beta1 = (const float*)d_in[11]; const float* gamma1 = (const float*)d_in[12];
    const float* beta2 = (const float*)d_in[13]; const float* gamma2 = (const float*)d_in[14];
    const float* beta3 = (const float*)d_in[15]; const float* gamma3 = (const float*)d_in[16];

    float* out = (float*)d_out;
    float* ws = (float*)d_ws;
    float* cnt   = ws + OFF_CNT;
    float* scale = ws + OFF_SCALE;
    float* m1 = ws + OFF_M1;
    float* m2 = ws + OFF_M2;
    float* m3 = ws + OFF_M3;
    float* t1 = ws + OFF_T1;
    float* y1 = ws + OFF_Y1;
    float* t2 = ws + OFF_T2;
    float* y2 = ws + OFF_Y2;
    float* t3 = ws + OFF_T3;
    float* y3 = ws + OFF_Y3;

    hipMemsetAsync(cnt, 0, 6 * sizeof(float), stream);

    qmean_kernel<<<4, 256, 0, stream>>>(QF, out + OUT_Q, scale);
    mask_pool1_kernel<<<256, 256, 0, stream>>>(x_feat, m1, cnt + 0);
    pool_kernel<<<32, 256, 0, stream>>>(m1, m2, cnt + 2, D1);
    pool_kernel<<<4, 256, 0, stream>>>(m2, m3, cnt + 4, D2);
    writek_kernel<<<1, 64, 0, stream>>>(cnt, out + OUT_K);

    // Stage 1: conv1 (4->32, 64->32, s2) + GDN1
    // conv1: blocks = 2b * (32/16) co-chunks * 128 tiles = 512
    conv_tile_kernel<4, 32, 16, 64, 32, 2, false>
        <<<512, 256, 0, stream>>>(x_feat, w1, b1, m1, nullptr, t1);
    // gdn1: blocks = 2 * 2 * 128 = 512
    conv_tile_kernel<32, 32, 16, 32, 32, 1, true>
        <<<512, 256, 0, stream>>>(t1, gamma1, beta1, nullptr, scale, y1);

    // Stage 2: conv2 (32->64, 32->16, s2) + GDN2
    // conv2: blocks = 2 * (64/8) * 16 = 256
    conv_tile_kernel<32, 64, 8, 32, 16, 2, false>
        <<<256, 256, 0, stream>>>(y1, w2, b2, m2, nullptr, t2);
    // gdn2: blocks = 2 * 8 * 16 = 256
    conv_tile_kernel<64, 64, 8, 16, 16, 1, true>
        <<<256, 256, 0, stream>>>(t2, gamma2, beta2, nullptr, scale, y2);

    // Stage 3: conv3 (64->96, 16->8, s2) + GDN3
    // conv3: blocks = 2 * (96/4) * 2 = 96
    conv_tile_kernel<64, 96, 4, 16, 8, 2, false>
        <<<96, 256, 0, stream>>>(y2, w3, b3, m3, nullptr, t3);
    // gdn3: blocks = 2 * 24 * 2 = 96
    conv_tile_kernel<96, 96, 4, 8, 8, 1, true>
        <<<96, 256, 0, stream>>>(t3, gamma3, beta3, nullptr, scale, y3);

    // Stage 4: conv4 (96->128, 8->8, s1): blocks = 2 * (128/4) * 2 = 128
    conv_tile_kernel<96, 128, 4, 8, 8, 1, false>
        <<<128, 256, 0, stream>>>(y3, w4, b4, m3, nullptr, out + OUT_X);
}

// Round 3
// 1244.330 us; speedup vs baseline: 6.2550x; 2.6987x over previous
//
#include <hip/hip_runtime.h>
#include <math.h>

// Problem constants
constexpr int Bn  = 2;
constexpr int CIN = 4;
constexpr int MQn = 1024;
constexpr int D0 = 64, D1 = 32, D2 = 16, D3 = 8;

// Output layout (floats): x [2,128,8,8,8] = 131072, q [1,2,2] = 4, k [3,2] = 6
constexpr int OUT_X = 0;
constexpr int OUT_Q = 131072;
constexpr int OUT_K = 131076;

// Workspace layout (floats)
constexpr size_t OFF_CNT   = 0;                 // c0[2], c1[2], c2[2]
constexpr size_t OFF_SCALE = 6;                 // scale[2]
constexpr size_t OFF_M1    = 8;                   // 2*32^3
constexpr size_t OFF_M2    = OFF_M1 + 65536;      // 2*16^3
constexpr size_t OFF_M3    = OFF_M2 + 8192;       // 2*8^3
constexpr size_t OFF_T1    = OFF_M3 + 1024;       // 2*32*32^3
constexpr size_t OFF_Y1    = OFF_T1 + 2097152;
constexpr size_t OFF_T2    = OFF_Y1 + 2097152;    // 2*64*16^3
constexpr size_t OFF_D2    = OFF_T2 + 524288;
constexpr size_t OFF_Y2    = OFF_D2 + 524288;
constexpr size_t OFF_T3    = OFF_Y2 + 524288;     // 2*96*8^3
constexpr size_t OFF_D3    = OFF_T3 + 98304;
constexpr size_t OFF_Y3    = OFF_D3 + 98304;
// transposed weights, layout [chunk][ci][tap][CO_TILE]
constexpr size_t OFF_W1T   = OFF_Y3 + 98304;      // 32*4*125   = 16000
constexpr size_t OFF_G1T   = OFF_W1T + 16000;     // 32*32*125  = 128000
constexpr size_t OFF_W2T   = OFF_G1T + 128000;    // 64*32*125  = 256000
constexpr size_t OFF_G2T   = OFF_W2T + 256000;    // 64*64*125  = 512000
constexpr size_t OFF_W3T   = OFF_G2T + 512000;    // 96*64*125  = 768000
constexpr size_t OFF_G3T   = OFF_W3T + 768000;    // 96*96*125  = 1152000
constexpr size_t OFF_W4T   = OFF_G3T + 1152000;   // 128*96*125 = 1536000
// end ~ 10.5M floats (~42 MB)

__global__ void qmean_kernel(const float* __restrict__ QF, float* __restrict__ out_q,
                             float* __restrict__ scale) {
    int b = blockIdx.x >> 1, c = blockIdx.x & 1;
    float s = 0.f;
    for (int m = threadIdx.x; m < MQn; m += blockDim.x)
        s += QF[(b * MQn + m) * 2 + c];
    __shared__ float sh[256];
    sh[threadIdx.x] = s;
    __syncthreads();
    for (int st = 128; st > 0; st >>= 1) {
        if (threadIdx.x < st) sh[threadIdx.x] += sh[threadIdx.x + st];
        __syncthreads();
    }
    if (threadIdx.x == 0) {
        float mean = sh[0] / (float)MQn;
        out_q[b * 2 + c] = mean;
        if (c == 0) scale[b] = mean;
    }
}

// Derive m0 from x_feat (any channel nonzero), pool to m1, count c0.
__global__ void mask_pool1_kernel(const float* __restrict__ xf, float* __restrict__ m1,
                                  float* __restrict__ c0) {
    int idx = blockIdx.x * blockDim.x + threadIdx.x;   // 0..65535
    int b = idx >> 15;
    int v = idx & 32767;
    int oz = v >> 10, oy = (v >> 5) & 31, ox = v & 31;
    float cnt = 0.f, mx = 0.f;
    for (int dz = 0; dz < 2; ++dz)
        for (int dy = 0; dy < 2; ++dy)
            for (int dx = 0; dx < 2; ++dx) {
                int z = 2 * oz + dz, y = 2 * oy + dy, x = 2 * ox + dx;
                size_t base = (size_t)b * CIN * D0 * D0 * D0 + ((size_t)z * D0 + y) * D0 + x;
                bool occ = false;
                for (int c = 0; c < CIN; ++c)
                    occ = occ || (xf[base + (size_t)c * D0 * D0 * D0] != 0.f);
                if (occ) { cnt += 1.f; mx = 1.f; }
            }
    m1[idx] = mx;
    __shared__ float sh[256];
    sh[threadIdx.x] = cnt;
    __syncthreads();
    for (int st = 128; st > 0; st >>= 1) {
        if (threadIdx.x < st) sh[threadIdx.x] += sh[threadIdx.x + st];
        __syncthreads();
    }
    if (threadIdx.x == 0) atomicAdd(&c0[b], sh[0]);
}

__global__ void pool_kernel(const float* __restrict__ min_, float* __restrict__ mout,
                            float* __restrict__ cacc, int Din) {
    int Do = Din >> 1;
    int per = Do * Do * Do;
    int idx = blockIdx.x * blockDim.x + threadIdx.x;
    int b = idx / per;
    int v = idx % per;
    int oz = v / (Do * Do), oy = (v / Do) % Do, ox = v % Do;
    float s = 0.f, mx = 0.f;
    for (int dz = 0; dz < 2; ++dz)
        for (int dy = 0; dy < 2; ++dy)
            for (int dx = 0; dx < 2; ++dx) {
                float val = min_[(((size_t)b * Din + 2 * oz + dz) * Din + 2 * oy + dy) * Din + 2 * ox + dx];
                s += val;
                mx = fmaxf(mx, val);
            }
    mout[idx] = mx;
    __shared__ float sh[256];
    sh[threadIdx.x] = s;
    __syncthreads();
    for (int st = 128; st > 0; st >>= 1) {
        if (threadIdx.x < st) sh[threadIdx.x] += sh[threadIdx.x + st];
        __syncthreads();
    }
    if (threadIdx.x == 0) atomicAdd(&cacc[b], sh[0]);
}

__global__ void writek_kernel(const float* __restrict__ cnt, float* __restrict__ outk) {
    int i = threadIdx.x;
    if (i < 6) {
        int row = i >> 1, b = i & 1;  // row0=c2, row1=c1, row2=c0
        float v = (row == 0) ? cnt[4 + b] : (row == 1 ? cnt[2 + b] : cnt[b]);
        outk[i] = v;
    }
}

// Transpose weights [co][ci][tap] -> [chunk][ci][tap][j] (j = co within chunk, contiguous)
template<int CINt, int COUTt, int CO_TILE>
__global__ __launch_bounds__(256) void wtrans_kernel(const float* __restrict__ w,
                                                     float* __restrict__ wt) {
    constexpr int TOTAL = COUTt * CINt * 125;
    int idx = blockIdx.x * 256 + threadIdx.x;
    if (idx >= TOTAL) return;
    int j = idx % CO_TILE;
    int t = idx / CO_TILE;
    int tap = t % 125; t /= 125;
    int ci = t % CINt;
    int chunk = t / CINt;
    int co = chunk * CO_TILE + j;
    wt[idx] = w[((size_t)co * CINt + ci) * 125 + tap];
}

// Tiled 5x5x5 conv, pad 2. Block = (batch, ci-group, co-chunk, spatial tile 4x8x8).
// Weights pre-transposed so each tap's CO_TILE weights are contiguous (-> s_load_dwordxN).
// STRIDE==2 uses x-parity-split LDS layout (even|odd half rows) -> conflict-free reads.
// CIG==1: full epilogue inline. CIG>1: partial accumulation via atomicAdd (no bias/epi).
template<int CINt, int COUTt, int CO_TILE, int DIN, int DOUT, int STRIDE, bool GDN, int CIG>
__global__ __launch_bounds__(256) void conv_tile_kernel(
    const float* __restrict__ in, const float* __restrict__ wt,
    const float* __restrict__ bb,      // bias (conv) or beta (gdn); unused if CIG>1
    const float* __restrict__ mask,    // conv full-epilogue only
    const float* __restrict__ scale,   // gdn full-epilogue only
    float* __restrict__ out)
{
    constexpr int TZ = 4, TY = 8, TX = 8;
    constexpr int LZ = (STRIDE == 1) ? TZ + 4 : 2 * TZ + 3;   // 8 | 11
    constexpr int LY = (STRIDE == 1) ? TY + 4 : 2 * TY + 3;   // 12 | 19
    constexpr int LX = (STRIDE == 1) ? TX + 4 : 2 * TX + 3;   // 12 | 19
    constexpr int LXP = (STRIDE == 2) ? (LX + 1) / 2 : 0;     // 10
    constexpr int ROWLEN = (STRIDE == 2) ? 2 * LXP : LX;      // 20 | 12
    constexpr int LN = LZ * LY * ROWLEN;
    constexpr int NTZ = DOUT / TZ, NTY = DOUT / TY, NTX = DOUT / TX;
    constexpr int NT = NTZ * NTY * NTX;
    constexpr int NCH = COUTt / CO_TILE;
    constexpr int CIPER = CINt / CIG;
    __shared__ float sh[LN];

    int tile  = blockIdx.x % NT;
    int chunk = (blockIdx.x / NT) % NCH;
    int cig   = (blockIdx.x / (NT * NCH)) % CIG;
    int b     = blockIdx.x / (NT * NCH * CIG);
    int tz0 = (tile / (NTY * NTX)) * TZ;
    int ty0 = ((tile / NTX) % NTY) * TY;
    int tx0 = (tile % NTX) * TX;
    int co0 = chunk * CO_TILE;

    int tid = threadIdx.x;
    int tx = tid & (TX - 1);
    int ty = (tid >> 3) & (TY - 1);
    int tz = tid >> 6;

    float acc[CO_TILE];
#pragma unroll
    for (int j = 0; j < CO_TILE; ++j) acc[j] = 0.f;

    int iz0 = tz0 * STRIDE - 2, iy0 = ty0 * STRIDE - 2, ix0 = tx0 * STRIDE - 2;

    for (int ci = cig * CIPER; ci < (cig + 1) * CIPER; ++ci) {
        const float* inp = in + (size_t)(b * CINt + ci) * DIN * DIN * DIN;
        __syncthreads();
        for (int i = tid; i < LN; i += 256) {
            int c = i % ROWLEN; int rem = i / ROWLEN;
            int ly = rem % LY, lz = rem / LY;
            int lx;
            if (STRIDE == 2) { int p = c / LXP, xp = c % LXP; lx = 2 * xp + p; }
            else lx = c;
            float v = 0.f;
            int gz = iz0 + lz, gy = iy0 + ly, gx = ix0 + lx;
            if (lx < LX && (unsigned)gz < (unsigned)DIN && (unsigned)gy < (unsigned)DIN &&
                (unsigned)gx < (unsigned)DIN)
                v = inp[((size_t)gz * DIN + gy) * DIN + gx];
            sh[i] = GDN ? v * v : v;
        }
        __syncthreads();
        const float* wci = wt + (size_t)(chunk * CINt + ci) * 125 * CO_TILE;
        for (int kz = 0; kz < 5; ++kz) {
            for (int ky = 0; ky < 5; ++ky) {
                int rowbase = ((tz * STRIDE + kz) * LY + ty * STRIDE + ky) * ROWLEN;
                const float* wrow = wci + (size_t)((kz * 5 + ky) * 5) * CO_TILE;
#pragma unroll
                for (int kx = 0; kx < 5; ++kx) {
                    int off = (STRIDE == 2)
                              ? rowbase + (kx & 1) * LXP + tx + (kx >> 1)
                              : rowbase + tx + kx;
                    float v = sh[off];
                    const float* wp = wrow + kx * CO_TILE;
#pragma unroll
                    for (int j = 0; j < CO_TILE; ++j)
                        acc[j] += v * wp[j];
                }
            }
        }
    }

    int z = tz0 + tz, y = ty0 + ty, x = tx0 + tx;
    size_t sp = ((size_t)z * DOUT + y) * DOUT + x;
    if (CIG > 1) {
#pragma unroll
        for (int j = 0; j < CO_TILE; ++j) {
            size_t oidx = (size_t)(b * COUTt + co0 + j) * DOUT * DOUT * DOUT + sp;
            atomicAdd(&out[oidx], acc[j]);
        }
    } else if (GDN) {
        float sc = scale[b];
#pragma unroll
        for (int j = 0; j < CO_TILE; ++j) {
            int co = co0 + j;
            size_t oidx = (size_t)(b * COUTt + co) * DOUT * DOUT * DOUT + sp;
            float tv = in[oidx];
            out[oidx] = tv * rsqrtf(bb[co] + acc[j]) * sc;
        }
    } else {
        float mval = mask[(size_t)b * DOUT * DOUT * DOUT + sp];
#pragma unroll
        for (int j = 0; j < CO_TILE; ++j) {
            int co = co0 + j;
            size_t oidx = (size_t)(b * COUTt + co) * DOUT * DOUT * DOUT + sp;
            out[oidx] = (acc[j] + bb[co]) * mval;
        }
    }
}

// Epilogues for ci-split partial kernels
template<int COUTt, int DOUT>
__global__ __launch_bounds__(256) void conv_epi_kernel(float* __restrict__ buf,
        const float* __restrict__ bias, const float* __restrict__ mask) {
    constexpr int VOX = DOUT * DOUT * DOUT;
    int idx = blockIdx.x * 256 + threadIdx.x;
    if (idx >= Bn * COUTt * VOX) return;
    int sp = idx % VOX;
    int co = (idx / VOX) % COUTt;
    int b = idx / (VOX * COUTt);
    buf[idx] = (buf[idx] + bias[co]) * mask[b * VOX + sp];
}

template<int COUTt, int DOUT>
__global__ __launch_bounds__(256) void gdn_epi_kernel(const float* __restrict__ t,
        const float* __restrict__ den, const float* __restrict__ beta,
        const float* __restrict__ scale, float* __restrict__ y) {
    constexpr int VOX = DOUT * DOUT * DOUT;
    int idx = blockIdx.x * 256 + threadIdx.x;
    if (idx >= Bn * COUTt * VOX) return;
    int co = (idx / VOX) % COUTt;
    int b = idx / (VOX * COUTt);
    y[idx] = t[idx] * rsqrtf(beta[co] + den[idx]) * scale[b];
}

extern "C" void kernel_launch(void* const* d_in, const int* in_sizes, int n_in,
                              void* d_out, int out_size, void* d_ws, size_t ws_size,
                              hipStream_t stream) {
    const float* x_feat = (const float*)d_in[0];
    const float* QF     = (const float*)d_in[2];
    const float* w1 = (const float*)d_in[3];  const float* b1 = (const float*)d_in[4];
    const float* w2 = (const float*)d_in[5];  const float* b2 = (const float*)d_in[6];
    const float* w3 = (const float*)d_in[7];  const float* b3 = (const float*)d_in[8];
    const float* w4 = (const float*)d_in[9];  const float* b4 = (const float*)d_in[10];
    const float* beta1 = (const float*)d_in[11]; const float* gamma1 = (const float*)d_in[12];
    const float* beta2 = (const float*)d_in[13]; const float* gamma2 = (const float*)d_in[14];
    const float* beta3 = (const float*)d_in[15]; const float* gamma3 = (const float*)d_in[16];

    float* out = (float*)d_out;
    float* ws = (float*)d_ws;
    float* cnt   = ws + OFF_CNT;
    float* scale = ws + OFF_SCALE;
    float* m1 = ws + OFF_M1;  float* m2 = ws + OFF_M2;  float* m3 = ws + OFF_M3;
    float* t1 = ws + OFF_T1;  float* y1 = ws + OFF_Y1;
    float* t2 = ws + OFF_T2;  float* d2 = ws + OFF_D2;  float* y2 = ws + OFF_Y2;
    float* t3 = ws + OFF_T3;  float* d3 = ws + OFF_D3;  float* y3 = ws + OFF_Y3;
    float* w1T = ws + OFF_W1T; float* g1T = ws + OFF_G1T;
    float* w2T = ws + OFF_W2T; float* g2T = ws + OFF_G2T;
    float* w3T = ws + OFF_W3T; float* g3T = ws + OFF_G3T;
    float* w4T = ws + OFF_W4T;

    hipMemsetAsync(cnt, 0, 6 * sizeof(float), stream);
    hipMemsetAsync(t2, 0, 524288 * sizeof(float), stream);
    hipMemsetAsync(d2, 0, 524288 * sizeof(float), stream);
    hipMemsetAsync(t3, 0, 98304 * sizeof(float), stream);
    hipMemsetAsync(d3, 0, 98304 * sizeof(float), stream);
    hipMemsetAsync(out + OUT_X, 0, 131072 * sizeof(float), stream);

    qmean_kernel<<<4, 256, 0, stream>>>(QF, out + OUT_Q, scale);
    mask_pool1_kernel<<<256, 256, 0, stream>>>(x_feat, m1, cnt + 0);
    pool_kernel<<<32, 256, 0, stream>>>(m1, m2, cnt + 2, D1);
    pool_kernel<<<4, 256, 0, stream>>>(m2, m3, cnt + 4, D2);
    writek_kernel<<<1, 64, 0, stream>>>(cnt, out + OUT_K);

    // weight transposes
    wtrans_kernel<4, 32, 16><<<(16000 + 255) / 256, 256, 0, stream>>>(w1, w1T);
    wtrans_kernel<32, 32, 16><<<(128000 + 255) / 256, 256, 0, stream>>>(gamma1, g1T);
    wtrans_kernel<32, 64, 8><<<(256000 + 255) / 256, 256, 0, stream>>>(w2, w2T);
    wtrans_kernel<64, 64, 8><<<(512000 + 255) / 256, 256, 0, stream>>>(gamma2, g2T);
    wtrans_kernel<64, 96, 8><<<(768000 + 255) / 256, 256, 0, stream>>>(w3, w3T);
    wtrans_kernel<96, 96, 8><<<(1152000 + 255) / 256, 256, 0, stream>>>(gamma3, g3T);
    wtrans_kernel<96, 128, 8><<<(1536000 + 255) / 256, 256, 0, stream>>>(w4, w4T);

    // Stage 1: conv1 (4->32, 64->32, s2) + GDN1, full epilogue inline
    conv_tile_kernel<4, 32, 16, 64, 32, 2, false, 1>
        <<<512, 256, 0, stream>>>(x_feat, w1T, b1, m1, nullptr, t1);
    conv_tile_kernel<32, 32, 16, 32, 32, 1, true, 1>
        <<<512, 256, 0, stream>>>(t1, g1T, beta1, nullptr, scale, y1);

    // Stage 2: conv2 (32->64, s2, ci-split x2) + GDN2 (ci-split x4)
    conv_tile_kernel<32, 64, 8, 32, 16, 2, false, 2>
        <<<512, 256, 0, stream>>>(y1, w2T, nullptr, nullptr, nullptr, t2);
    conv_epi_kernel<64, 16><<<2048, 256, 0, stream>>>(t2, b2, m2);
    conv_tile_kernel<64, 64, 8, 16, 16, 1, true, 4>
        <<<1024, 256, 0, stream>>>(t2, g2T, nullptr, nullptr, nullptr, d2);
    gdn_epi_kernel<64, 16><<<2048, 256, 0, stream>>>(t2, d2, beta2, scale, y2);

    // Stage 3: conv3 (64->96, s2, ci-split x4) + GDN3 (ci-split x6)
    conv_tile_kernel<64, 96, 8, 16, 8, 2, false, 4>
        <<<192, 256, 0, stream>>>(y2, w3T, nullptr, nullptr, nullptr, t3);
    conv_epi_kernel<96, 8><<<384, 256, 0, stream>>>(t3, b3, m3);
    conv_tile_kernel<96, 96, 8, 8, 8, 1, true, 6>
        <<<288, 256, 0, stream>>>(t3, g3T, nullptr, nullptr, nullptr, d3);
    gdn_epi_kernel<96, 8><<<384, 256, 0, stream>>>(t3, d3, beta3, scale, y3);

    // Stage 4: conv4 (96->128, s1, ci-split x6) straight to output + epilogue
    conv_tile_kernel<96, 128, 8, 8, 8, 1, false, 6>
        <<<384, 256, 0, stream>>>(y3, w4T, nullptr, nullptr, nullptr, out + OUT_X);
    conv_epi_kernel<128, 8><<<512, 256, 0, stream>>>(out + OUT_X, b4, m3);
}

// Round 4
// 877.704 us; speedup vs baseline: 8.8678x; 1.4177x over previous
//
#include <hip/hip_runtime.h>
#include <math.h>

// Problem constants
constexpr int Bn  = 2;
constexpr int CIN = 4;
constexpr int MQn = 1024;
constexpr int D0 = 64, D1 = 32, D2 = 16, D3 = 8;

// Output layout (floats): x [2,128,8,8,8] = 131072, q [1,2,2] = 4, k [3,2] = 6
constexpr int OUT_X = 0;
constexpr int OUT_Q = 131072;
constexpr int OUT_K = 131076;

// Workspace layout (floats)
constexpr size_t OFF_CNT   = 0;       // c0[2], c1[2], c2[2]
constexpr size_t OFF_ZERO  = 8;       // guaranteed-zero word for DMA padding
constexpr size_t OFF_SCALE = 10;
constexpr size_t OFF_M1    = 16;                  // 2*32^3
constexpr size_t OFF_M2    = OFF_M1 + 65536;      // 2*16^3
constexpr size_t OFF_M3    = OFF_M2 + 8192;       // 2*8^3
constexpr size_t OFF_T1    = OFF_M3 + 1024;       // 2*32*32^3
constexpr size_t OFF_D1    = OFF_T1 + 2097152;
constexpr size_t OFF_Y1    = OFF_D1 + 2097152;
constexpr size_t OFF_T2    = OFF_Y1 + 2097152;    // 2*64*16^3
constexpr size_t OFF_D2    = OFF_T2 + 524288;
constexpr size_t OFF_Y2    = OFF_D2 + 524288;
constexpr size_t OFF_T3    = OFF_Y2 + 524288;     // 2*96*8^3
constexpr size_t OFF_D3    = OFF_T3 + 98304;
constexpr size_t OFF_Y3    = OFF_D3 + 98304;
// transposed weights, layout [chunk][ci][tap][CO_TILE=16]
constexpr size_t OFF_W1T   = OFF_Y3 + 98304;      // 16000
constexpr size_t OFF_G1T   = OFF_W1T + 16000;     // 128000
constexpr size_t OFF_W2T   = OFF_G1T + 128000;    // 256000
constexpr size_t OFF_G2T   = OFF_W2T + 256000;    // 512000
constexpr size_t OFF_W3T   = OFF_G2T + 512000;    // 768000
constexpr size_t OFF_G3T   = OFF_W3T + 768000;    // 1152000
constexpr size_t OFF_W4T   = OFF_G3T + 1152000;   // 1536000
// end ~12.6M floats (~50.4 MB)

__device__ __forceinline__ void async_copy4(const float* g, float* l) {
    __builtin_amdgcn_global_load_lds(
        (const __attribute__((address_space(1))) void*)g,
        (__attribute__((address_space(3))) void*)l, 4, 0, 0);
}

__global__ void qmean_kernel(const float* __restrict__ QF, float* __restrict__ out_q,
                             float* __restrict__ scale) {
    int b = blockIdx.x >> 1, c = blockIdx.x & 1;
    float s = 0.f;
    for (int m = threadIdx.x; m < MQn; m += blockDim.x)
        s += QF[(b * MQn + m) * 2 + c];
    __shared__ float sh[256];
    sh[threadIdx.x] = s;
    __syncthreads();
    for (int st = 128; st > 0; st >>= 1) {
        if (threadIdx.x < st) sh[threadIdx.x] += sh[threadIdx.x + st];
        __syncthreads();
    }
    if (threadIdx.x == 0) {
        float mean = sh[0] / (float)MQn;
        out_q[b * 2 + c] = mean;
        if (c == 0) scale[b] = mean;
    }
}

// Derive m0 from x_feat (any channel nonzero), pool to m1, count c0.
__global__ void mask_pool1_kernel(const float* __restrict__ xf, float* __restrict__ m1,
                                  float* __restrict__ c0) {
    int idx = blockIdx.x * blockDim.x + threadIdx.x;   // 0..65535
    int b = idx >> 15;
    int v = idx & 32767;
    int oz = v >> 10, oy = (v >> 5) & 31, ox = v & 31;
    float cnt = 0.f, mx = 0.f;
    for (int dz = 0; dz < 2; ++dz)
        for (int dy = 0; dy < 2; ++dy)
            for (int dx = 0; dx < 2; ++dx) {
                int z = 2 * oz + dz, y = 2 * oy + dy, x = 2 * ox + dx;
                size_t base = (size_t)b * CIN * D0 * D0 * D0 + ((size_t)z * D0 + y) * D0 + x;
                bool occ = false;
                for (int c = 0; c < CIN; ++c)
                    occ = occ || (xf[base + (size_t)c * D0 * D0 * D0] != 0.f);
                if (occ) { cnt += 1.f; mx = 1.f; }
            }
    m1[idx] = mx;
    __shared__ float sh[256];
    sh[threadIdx.x] = cnt;
    __syncthreads();
    for (int st = 128; st > 0; st >>= 1) {
        if (threadIdx.x < st) sh[threadIdx.x] += sh[threadIdx.x + st];
        __syncthreads();
    }
    if (threadIdx.x == 0) atomicAdd(&c0[b], sh[0]);
}

__global__ void pool_kernel(const float* __restrict__ min_, float* __restrict__ mout,
                            float* __restrict__ cacc, int Din) {
    int Do = Din >> 1;
    int per = Do * Do * Do;
    int idx = blockIdx.x * blockDim.x + threadIdx.x;
    int b = idx / per;
    int v = idx % per;
    int oz = v / (Do * Do), oy = (v / Do) % Do, ox = v % Do;
    float s = 0.f, mx = 0.f;
    for (int dz = 0; dz < 2; ++dz)
        for (int dy = 0; dy < 2; ++dy)
            for (int dx = 0; dx < 2; ++dx) {
                float val = min_[(((size_t)b * Din + 2 * oz + dz) * Din + 2 * oy + dy) * Din + 2 * ox + dx];
                s += val;
                mx = fmaxf(mx, val);
            }
    mout[idx] = mx;
    __shared__ float sh[256];
    sh[threadIdx.x] = s;
    __syncthreads();
    for (int st = 128; st > 0; st >>= 1) {
        if (threadIdx.x < st) sh[threadIdx.x] += sh[threadIdx.x + st];
        __syncthreads();
    }
    if (threadIdx.x == 0) atomicAdd(&cacc[b], sh[0]);
}

__global__ void writek_kernel(const float* __restrict__ cnt, float* __restrict__ outk) {
    int i = threadIdx.x;
    if (i < 6) {
        int row = i >> 1, b = i & 1;  // row0=c2, row1=c1, row2=c0
        float v = (row == 0) ? cnt[4 + b] : (row == 1 ? cnt[2 + b] : cnt[b]);
        outk[i] = v;
    }
}

// Coalesced-read transpose: w[co][ci][tap] -> wt[chunk][ci][tap][j]
template<int CINt, int COUTt, int CO_TILE>
__global__ __launch_bounds__(256) void wtrans_kernel(const float* __restrict__ w,
                                                     float* __restrict__ wt) {
    constexpr int TOTAL = COUTt * CINt * 125;
    int idx = blockIdx.x * 256 + threadIdx.x;
    if (idx >= TOTAL) return;
    int co = idx / (CINt * 125);
    int r  = idx % (CINt * 125);
    int ci = r / 125, tap = r % 125;
    int chunk = co / CO_TILE, j = co % CO_TILE;
    wt[(((size_t)chunk * CINt + ci) * 125 + tap) * CO_TILE + j] = w[idx];
}

// Tiled 5x5x5 conv, pad 2. Block = (batch, ci-group, co-chunk, spatial tile 4x8x8).
// Double-buffered LDS staging via global_load_lds (per-lane gaddr, lane-contiguous LDS),
// one barrier per ci: stage(ci+1) issued before compute(ci).
// Weights pre-transposed -> wave-uniform s_load_dwordx16 per tap.
// STRIDE==2 uses x-parity-split LDS layout (conflict-light reads).
// GDN squares the staged value at use (acc += v*v*w).
// CIG==1: full conv epilogue inline. CIG>1: atomicAdd partials.
template<int CINt, int COUTt, int CO_TILE, int DIN, int DOUT, int STRIDE, bool GDN, int CIG>
__global__ __launch_bounds__(256) void conv_tile_kernel(
    const float* __restrict__ in, const float* __restrict__ wt,
    const float* __restrict__ bb,      // bias (conv CIG==1 only)
    const float* __restrict__ mask,    // conv CIG==1 only
    const float* __restrict__ zerow,   // zero word for padding DMA
    float* __restrict__ out)
{
    constexpr int TZ = 4, TY = 8, TX = 8;
    constexpr int LZ = (STRIDE == 1) ? TZ + 4 : 2 * TZ + 3;   // 8 | 11
    constexpr int LY = (STRIDE == 1) ? TY + 4 : 2 * TY + 3;   // 12 | 19
    constexpr int LX = (STRIDE == 1) ? TX + 4 : 2 * TX + 3;   // 12 | 19
    constexpr int LXP = (STRIDE == 2) ? (LX + 1) / 2 : 0;     // 10
    constexpr int ROWLEN = (STRIDE == 2) ? 2 * LXP : LX;      // 20 | 12
    constexpr int LN = LZ * LY * ROWLEN;                      // 1152 | 4180
    constexpr int NLOAD = (LN + 255) / 256;                   // 5 | 17
    constexpr int PADN = NLOAD * 256;
    constexpr int NTZ = DOUT / TZ, NTY = DOUT / TY, NTX = DOUT / TX;
    constexpr int NT = NTZ * NTY * NTX;
    constexpr int NCH = COUTt / CO_TILE;
    constexpr int CIPER = CINt / CIG;
    __shared__ float sh[2][PADN];

    int tile  = blockIdx.x % NT;
    int chunk = (blockIdx.x / NT) % NCH;
    int cig   = (blockIdx.x / (NT * NCH)) % CIG;
    int b     = blockIdx.x / (NT * NCH * CIG);
    int tz0 = (tile / (NTY * NTX)) * TZ;
    int ty0 = ((tile / NTX) % NTY) * TY;
    int tx0 = (tile % NTX) * TX;
    int co0 = chunk * CO_TILE;

    int tid = threadIdx.x;
    int tx = tid & (TX - 1);
    int ty = (tid >> 3) & (TY - 1);
    int tz = tid >> 6;

    int iz0 = tz0 * STRIDE - 2, iy0 = ty0 * STRIDE - 2, ix0 = tx0 * STRIDE - 2;

    // Precompute per-thread staging offsets (same every ci)
    int goff[NLOAD];
#pragma unroll
    for (int k = 0; k < NLOAD; ++k) {
        int i = tid + k * 256;
        int c = i % ROWLEN; int rem = i / ROWLEN;
        int ly = rem % LY, lz = rem / LY;
        int lx;
        if (STRIDE == 2) { int p = c / LXP, xp = c % LXP; lx = 2 * xp + p; }
        else lx = c;
        int gz = iz0 + lz, gy = iy0 + ly, gx = ix0 + lx;
        bool valid = (i < LN) && (lx < LX) &&
                     (unsigned)gz < (unsigned)DIN && (unsigned)gy < (unsigned)DIN &&
                     (unsigned)gx < (unsigned)DIN;
        goff[k] = valid ? ((gz * DIN + gy) * DIN + gx) : -1;
    }

    int ci0 = cig * CIPER;
    auto stage = [&](int ci, int buf) {
        const float* base = in + (size_t)(b * CINt + ci) * DIN * DIN * DIN;
        float* dst = &sh[buf][0];
#pragma unroll
        for (int k = 0; k < NLOAD; ++k) {
            const float* g = (goff[k] >= 0) ? (base + goff[k]) : zerow;
            async_copy4(g, &dst[k * 256 + tid]);
        }
    };

    float acc[CO_TILE];
#pragma unroll
    for (int j = 0; j < CO_TILE; ++j) acc[j] = 0.f;

    stage(ci0, 0);
    for (int i = 0; i < CIPER; ++i) {
        int cur = i & 1;
        __syncthreads();                       // drains DMA for buf cur
        if (i + 1 < CIPER) stage(ci0 + i + 1, cur ^ 1);
        const float* shc = &sh[cur][0];
        const float* wci = wt + (size_t)(chunk * CINt + (ci0 + i)) * 125 * CO_TILE;
        for (int kz = 0; kz < 5; ++kz) {
            for (int ky = 0; ky < 5; ++ky) {
                int rowbase = ((tz * STRIDE + kz) * LY + ty * STRIDE + ky) * ROWLEN;
                const float* wrow = wci + (size_t)((kz * 5 + ky) * 5) * CO_TILE;
#pragma unroll
                for (int kx = 0; kx < 5; ++kx) {
                    int off = (STRIDE == 2)
                              ? rowbase + (kx & 1) * LXP + tx + (kx >> 1)
                              : rowbase + tx + kx;
                    float v = shc[off];
                    float vv = GDN ? v * v : v;
                    const float* wp = wrow + kx * CO_TILE;
#pragma unroll
                    for (int j = 0; j < CO_TILE; ++j)
                        acc[j] = fmaf(vv, wp[j], acc[j]);
                }
            }
        }
    }

    int z = tz0 + tz, y = ty0 + ty, x = tx0 + tx;
    size_t sp = ((size_t)z * DOUT + y) * DOUT + x;
    if (CIG > 1) {
#pragma unroll
        for (int j = 0; j < CO_TILE; ++j) {
            size_t oidx = (size_t)(b * COUTt + co0 + j) * DOUT * DOUT * DOUT + sp;
            atomicAdd(&out[oidx], acc[j]);
        }
    } else {
        float mval = mask[(size_t)b * DOUT * DOUT * DOUT + sp];
#pragma unroll
        for (int j = 0; j < CO_TILE; ++j) {
            int co = co0 + j;
            size_t oidx = (size_t)(b * COUTt + co) * DOUT * DOUT * DOUT + sp;
            out[oidx] = (acc[j] + bb[co]) * mval;
        }
    }
}

// Epilogues for ci-split partial kernels
template<int COUTt, int DOUT>
__global__ __launch_bounds__(256) void conv_epi_kernel(float* __restrict__ buf,
        const float* __restrict__ bias, const float* __restrict__ mask) {
    constexpr int VOX = DOUT * DOUT * DOUT;
    int idx = blockIdx.x * 256 + threadIdx.x;
    if (idx >= Bn * COUTt * VOX) return;
    int sp = idx % VOX;
    int co = (idx / VOX) % COUTt;
    int b = idx / (VOX * COUTt);
    buf[idx] = (buf[idx] + bias[co]) * mask[b * VOX + sp];
}

template<int COUTt, int DOUT>
__global__ __launch_bounds__(256) void gdn_epi_kernel(const float* __restrict__ t,
        const float* __restrict__ den, const float* __restrict__ beta,
        const float* __restrict__ scale, float* __restrict__ y) {
    constexpr int VOX = DOUT * DOUT * DOUT;
    int idx = blockIdx.x * 256 + threadIdx.x;
    if (idx >= Bn * COUTt * VOX) return;
    int co = (idx / VOX) % COUTt;
    int b = idx / (VOX * COUTt);
    y[idx] = t[idx] * rsqrtf(beta[co] + den[idx]) * scale[b];
}

extern "C" void kernel_launch(void* const* d_in, const int* in_sizes, int n_in,
                              void* d_out, int out_size, void* d_ws, size_t ws_size,
                              hipStream_t stream) {
    const float* x_feat = (const float*)d_in[0];
    const float* QF     = (const float*)d_in[2];
    const float* w1 = (const float*)d_in[3];  const float* b1 = (const float*)d_in[4];
    const float* w2 = (const float*)d_in[5];  const float* b2 = (const float*)d_in[6];
    const float* w3 = (const float*)d_in[7];  const float* b3 = (const float*)d_in[8];
    const float* w4 = (const float*)d_in[9];  const float* b4 = (const float*)d_in[10];
    const float* beta1 = (const float*)d_in[11]; const float* gamma1 = (const float*)d_in[12];
    const float* beta2 = (const float*)d_in[13]; const float* gamma2 = (const float*)d_in[14];
    const float* beta3 = (const float*)d_in[15]; const float* gamma3 = (const float*)d_in[16];

    float* out = (float*)d_out;
    float* ws = (float*)d_ws;
    float* cnt   = ws + OFF_CNT;
    float* zerow = ws + OFF_ZERO;
    float* scale = ws + OFF_SCALE;
    float* m1 = ws + OFF_M1;  float* m2 = ws + OFF_M2;  float* m3 = ws + OFF_M3;
    float* t1 = ws + OFF_T1;  float* d1 = ws + OFF_D1;  float* y1 = ws + OFF_Y1;
    float* t2 = ws + OFF_T2;  float* d2 = ws + OFF_D2;  float* y2 = ws + OFF_Y2;
    float* t3 = ws + OFF_T3;  float* d3 = ws + OFF_D3;  float* y3 = ws + OFF_Y3;
    float* w1T = ws + OFF_W1T; float* g1T = ws + OFF_G1T;
    float* w2T = ws + OFF_W2T; float* g2T = ws + OFF_G2T;
    float* w3T = ws + OFF_W3T; float* g3T = ws + OFF_G3T;
    float* w4T = ws + OFF_W4T;

    hipMemsetAsync(cnt, 0, 16 * sizeof(float), stream);     // cnt + zero word
    hipMemsetAsync(d1, 0, 2097152 * sizeof(float), stream);
    hipMemsetAsync(t2, 0, 524288 * sizeof(float), stream);
    hipMemsetAsync(d2, 0, 524288 * sizeof(float), stream);
    hipMemsetAsync(t3, 0, 98304 * sizeof(float), stream);
    hipMemsetAsync(d3, 0, 98304 * sizeof(float), stream);
    hipMemsetAsync(out + OUT_X, 0, 131072 * sizeof(float), stream);

    qmean_kernel<<<4, 256, 0, stream>>>(QF, out + OUT_Q, scale);
    mask_pool1_kernel<<<256, 256, 0, stream>>>(x_feat, m1, cnt + 0);
    pool_kernel<<<32, 256, 0, stream>>>(m1, m2, cnt + 2, D1);
    pool_kernel<<<4, 256, 0, stream>>>(m2, m3, cnt + 4, D2);
    writek_kernel<<<1, 64, 0, stream>>>(cnt, out + OUT_K);

    // weight transposes (coalesced reads)
    wtrans_kernel<4, 32, 16><<<63, 256, 0, stream>>>(w1, w1T);
    wtrans_kernel<32, 32, 16><<<500, 256, 0, stream>>>(gamma1, g1T);
    wtrans_kernel<32, 64, 16><<<1000, 256, 0, stream>>>(w2, w2T);
    wtrans_kernel<64, 64, 16><<<2000, 256, 0, stream>>>(gamma2, g2T);
    wtrans_kernel<64, 96, 16><<<3000, 256, 0, stream>>>(w3, w3T);
    wtrans_kernel<96, 96, 16><<<4500, 256, 0, stream>>>(gamma3, g3T);
    wtrans_kernel<96, 128, 16><<<6000, 256, 0, stream>>>(w4, w4T);

    // Stage 1: conv1 (4->32, 64->32, s2, inline epi) + GDN1 (ci-split x2)
    conv_tile_kernel<4, 32, 16, 64, 32, 2, false, 1>
        <<<512, 256, 0, stream>>>(x_feat, w1T, b1, m1, zerow, t1);
    conv_tile_kernel<32, 32, 16, 32, 32, 1, true, 2>
        <<<1024, 256, 0, stream>>>(t1, g1T, nullptr, nullptr, zerow, d1);
    gdn_epi_kernel<32, 32><<<8192, 256, 0, stream>>>(t1, d1, beta1, scale, y1);

    // Stage 2: conv2 (32->64, s2, ci-split x8) + GDN2 (ci-split x8)
    conv_tile_kernel<32, 64, 16, 32, 16, 2, false, 8>
        <<<1024, 256, 0, stream>>>(y1, w2T, nullptr, nullptr, zerow, t2);
    conv_epi_kernel<64, 16><<<2048, 256, 0, stream>>>(t2, b2, m2);
    conv_tile_kernel<64, 64, 16, 16, 16, 1, true, 8>
        <<<1024, 256, 0, stream>>>(t2, g2T, nullptr, nullptr, zerow, d2);
    gdn_epi_kernel<64, 16><<<2048, 256, 0, stream>>>(t2, d2, beta2, scale, y2);

    // Stage 3: conv3 (64->96, s2, ci-split x16) + GDN3 (ci-split x16)
    conv_tile_kernel<64, 96, 16, 16, 8, 2, false, 16>
        <<<384, 256, 0, stream>>>(y2, w3T, nullptr, nullptr, zerow, t3);
    conv_epi_kernel<96, 8><<<384, 256, 0, stream>>>(t3, b3, m3);
    conv_tile_kernel<96, 96, 16, 8, 8, 1, true, 16>
        <<<384, 256, 0, stream>>>(t3, g3T, nullptr, nullptr, zerow, d3);
    gdn_epi_kernel<96, 8><<<384, 256, 0, stream>>>(t3, d3, beta3, scale, y3);

    // Stage 4: conv4 (96->128, s1, ci-split x16) straight to output + epilogue
    conv_tile_kernel<96, 128, 16, 8, 8, 1, false, 16>
        <<<512, 256, 0, stream>>>(y3, w4T, nullptr, nullptr, zerow, out + OUT_X);
    conv_epi_kernel<128, 8><<<512, 256, 0, stream>>>(out + OUT_X, b4, m3);
}